// Round 1
// baseline (630.787 us; speedup 1.0000x reference)
//
#include <hip/hip_runtime.h>
#include <cstddef>
#include <cstdint>

#define NHEADS 8
#define TT 243
#define JJ 17
#define BB 8
#define CC 512
#define HD 64
#define MROWS 33048      // B*T*J
#define TJ 4131          // T*J
#define HJ 136           // H*J

typedef __attribute__((ext_vector_type(8))) short bf16x8;
typedef __attribute__((ext_vector_type(4))) float f32x4;

__device__ __forceinline__ unsigned short f2bf(float f) {
    unsigned u = __float_as_uint(f);
    unsigned r = (u + 0x7fff + ((u >> 16) & 1)) >> 16;   // RNE
    return (unsigned short)r;
}
__device__ __forceinline__ float b2f(unsigned short u) {
    return __uint_as_float(((unsigned)u) << 16);
}
__device__ __forceinline__ void async16(const void* g, void* l) {
    __builtin_amdgcn_global_load_lds(
        (const __attribute__((address_space(1))) void*)g,
        (__attribute__((address_space(3))) void*)l, 16, 0, 0);
}

// ---------------------------------------------------------------------------
// prep: x fp32 -> bf16 (same layout)
// ---------------------------------------------------------------------------
__global__ __launch_bounds__(256) void convert_x(
    const float* __restrict__ in, unsigned short* __restrict__ out, int n4)
{
    for (int i = blockIdx.x * 256 + threadIdx.x; i < n4; i += gridDim.x * 256) {
        const float4 v = *(const float4*)(in + (size_t)i * 4);
        ushort4 o;
        o.x = f2bf(v.x); o.y = f2bf(v.y); o.z = f2bf(v.z); o.w = f2bf(v.w);
        *(ushort4*)(out + (size_t)i * 4) = o;
    }
}

// ---------------------------------------------------------------------------
// prep: W fp32 [512][N] -> bf16 [N][512]  (transpose + convert)
// ---------------------------------------------------------------------------
__global__ __launch_bounds__(256) void transpose_w(
    const float* __restrict__ src, unsigned short* __restrict__ dst, int N)
{
    __shared__ unsigned short tile[64][65];
    const int tid = threadIdx.x;
    const int c = tid & 63, r4 = tid >> 6;
    const int n0 = blockIdx.x << 6, k0 = blockIdx.y << 6;
    #pragma unroll
    for (int p = 0; p < 16; ++p) {
        const int r = (p << 2) + r4;
        tile[r][c] = f2bf(src[(size_t)(k0 + r) * N + n0 + c]);
    }
    __syncthreads();
    #pragma unroll
    for (int p = 0; p < 16; ++p) {
        const int rr = (p << 2) + r4;
        dst[(size_t)(n0 + rr) * 512 + k0 + c] = tile[c][rr];
    }
}

// ---------------------------------------------------------------------------
// Kernel 1: bf16 MFMA GEMM  qkv = xb @ Wqkv  (Wqkvt pre-transposed [1536][512])
// ---------------------------------------------------------------------------
__global__ __launch_bounds__(256) void gemm_qkv(
    const unsigned short* __restrict__ xb, const unsigned short* __restrict__ wt,
    unsigned short* __restrict__ qb, unsigned short* __restrict__ kb,
    unsigned short* __restrict__ vb)
{
    __shared__ unsigned short As[128 * 32];
    __shared__ unsigned short Bs[128 * 32];
    __shared__ unsigned short Cq[4][16][72];
    const int tid = threadIdx.x;
    const int wave = tid >> 6, lane = tid & 63;
    const int m0 = blockIdx.y << 7, n0 = blockIdx.x << 7;
    const int wr = wave >> 1, wc = wave & 1;

    f32x4 acc[4][4];
    #pragma unroll
    for (int i = 0; i < 4; ++i)
        #pragma unroll
        for (int j = 0; j < 4; ++j) acc[i][j] = (f32x4){0.f, 0.f, 0.f, 0.f};

    const int srow = lane >> 2;
    const int sbyte = (lane & 3) << 4;
    const int arow0 = (wave << 5) + srow;
    const int arow1 = arow0 + 16;
    const size_t am0 = (size_t)min(m0 + arow0, MROWS - 1);
    const size_t am1 = (size_t)min(m0 + arow1, MROWS - 1);
    const char* xbb = (const char*)xb;
    const char* wtb = (const char*)wt;
    char* Asb = (char*)As;
    char* Bsb = (char*)Bs;

    for (int k0 = 0; k0 < 512; k0 += 32) {
        __syncthreads();
        async16(xbb + (am0 * 512 + k0) * 2 + sbyte, Asb + ((wave << 5) << 6));
        async16(xbb + (am1 * 512 + k0) * 2 + sbyte, Asb + (((wave << 5) + 16) << 6));
        async16(wtb + ((size_t)(n0 + arow0) * 512 + k0) * 2 + sbyte, Bsb + ((wave << 5) << 6));
        async16(wtb + ((size_t)(n0 + arow1) * 512 + k0) * 2 + sbyte, Bsb + (((wave << 5) + 16) << 6));
        __syncthreads();
        bf16x8 af[4], bfr[4];
        #pragma unroll
        for (int i = 0; i < 4; ++i)
            af[i] = *(const bf16x8*)&As[((wr << 6) + (i << 4) + (lane & 15)) * 32 + ((lane >> 4) << 3)];
        #pragma unroll
        for (int j = 0; j < 4; ++j)
            bfr[j] = *(const bf16x8*)&Bs[((wc << 6) + (j << 4) + (lane & 15)) * 32 + ((lane >> 4) << 3)];
        #pragma unroll
        for (int i = 0; i < 4; ++i)
            #pragma unroll
            for (int j = 0; j < 4; ++j)
                acc[i][j] = __builtin_amdgcn_mfma_f32_16x16x32_bf16(af[i], bfr[j], acc[i][j], 0, 0, 0);
    }

    const int nw = n0 + (wc << 6);
    const int which = nw >> 9;
    const int h = (nw >> 6) & 7;
    unsigned short* const dst = which == 0 ? qb : (which == 1 ? kb : vb);
    #pragma unroll
    for (int i = 0; i < 4; ++i) {
        #pragma unroll
        for (int j = 0; j < 4; ++j)
            #pragma unroll
            for (int r = 0; r < 4; ++r)
                Cq[wave][((lane >> 4) << 2) + r][(j << 4) + (lane & 15)] = f2bf(acc[i][j][r]);
        #pragma unroll
        for (int qq = 0; qq < 4; ++qq) {
            const int rr = (qq << 2) + (lane >> 4);
            const int ch = lane & 15;
            const ushort4 val = *(const ushort4*)&Cq[wave][rr][ch << 2];
            const int m = m0 + (wr << 6) + (i << 4) + rr;
            if (m < MROWS) {
                const int b = m / TJ; const int rm = m - b * TJ;
                const int t = rm / JJ; const int jj = rm - t * JJ;
                const size_t base = (((size_t)((b * NHEADS + h) * JJ + jj) * TT + t) << 6) + (ch << 2);
                *(ushort4*)(dst + base) = val;
            }
        }
    }
}

// ---------------------------------------------------------------------------
// vtrans: vb [bhj][t][64] -> vt [bhj][64][256] (d-major, zero-padded t,
// LINEAR layout — consumed straight from global/L2 by attn phase 3)
// ---------------------------------------------------------------------------
__global__ __launch_bounds__(256) void vtrans(
    const unsigned short* __restrict__ vb, unsigned short* __restrict__ vt)
{
    __shared__ unsigned short TL[64 * 264];
    const int tid = threadIdx.x;
    const int bhj = blockIdx.x;
    const unsigned short* src = vb + (size_t)bhj * TT * HD;

    {   // zero cols 240..255 (covers the t>=243 padding; 240..242 rewritten)
        const int d = tid >> 2, qq = tid & 3;
        *(ushort4*)(TL + d * 264 + 240 + (qq << 2)) = make_ushort4(0, 0, 0, 0);
    }
    __syncthreads();
    #pragma unroll
    for (int p = 0; p < 16; ++p) {
        const int idxq = tid + (p << 8);
        const int t = idxq >> 4;
        if (t < TT) {
            const int d0 = (idxq & 15) << 2;
            const ushort4 u = *(const ushort4*)(src + t * HD + d0);
            TL[(d0 + 0) * 264 + t] = u.x;
            TL[(d0 + 1) * 264 + t] = u.y;
            TL[(d0 + 2) * 264 + t] = u.z;
            TL[(d0 + 3) * 264 + t] = u.w;
        }
    }
    __syncthreads();
    unsigned short* dst = vt + ((size_t)bhj << 14);
    #pragma unroll
    for (int p = 0; p < 8; ++p) {
        const int cw = tid + (p << 8);           // 2048 chunk-writes
        const int d = cw >> 5, c = cw & 31;
        const ushort4 a = *(const ushort4*)(TL + d * 264 + (c << 3));
        const ushort4 bq = *(const ushort4*)(TL + d * 264 + (c << 3) + 4);
        *(ushort4*)(dst + (d << 8) + (c << 3)) = a;
        *(ushort4*)(dst + (d << 8) + (c << 3) + 4) = bq;
    }
}

// ---------------------------------------------------------------------------
// Kernel 2: MFMA attention. block = (bhj, 64-row tile), 4 waves.
// Phase1: wave w computes S[:, 64w..64w+64) = Q K^T via 16x16x32 mfma,
//         Q/K frags straight from global (K-major rows = frag layout).
// Phase2: row-parallel softmax + blend over row-major bf16 S in LDS.
// Phase3: O = P @ Vt, Vt read DIRECTLY from global (L2/L3-resident, 32KB/bhj).
// LDS = ST only (33.8KB) -> 4 blocks/CU (was 2 with VT staged).
// ---------------------------------------------------------------------------
__global__ __launch_bounds__(256, 4) void attn_mfma(
    const unsigned short* __restrict__ qb, const unsigned short* __restrict__ kb,
    const unsigned short* __restrict__ vt, const float* __restrict__ att,
    const float* __restrict__ wptr, unsigned short* __restrict__ ob)
{
    __shared__ unsigned short ST[64 * 264];   // S / P, row-major bf16

    const int tid = threadIdx.x;
    const int wave = tid >> 6, lane = tid & 63;
    const int tile = blockIdx.x & 3, bhj = blockIdx.x >> 2;
    const int row0 = tile << 6;

    const unsigned short* q = qb + (size_t)bhj * TT * HD;
    const unsigned short* k = kb + (size_t)bhj * TT * HD;
    const float* am = att + (size_t)bhj * TT * TT;
    const float w = wptr[0];

    // ---- Phase 1 ----
    const int lm = lane & 15, lk = lane >> 4;
    bf16x8 qf[4][2];
    #pragma unroll
    for (int mi = 0; mi < 4; ++mi) {
        const int r = min(row0 + (mi << 4) + lm, TT - 1);
        #pragma unroll
        for (int kb2 = 0; kb2 < 2; ++kb2)
            qf[mi][kb2] = *(const bf16x8*)(q + r * HD + (kb2 << 5) + (lk << 3));
    }
    f32x4 acc[4][4];
    #pragma unroll
    for (int mi = 0; mi < 4; ++mi)
        #pragma unroll
        for (int nj = 0; nj < 4; ++nj) acc[mi][nj] = (f32x4){0.f, 0.f, 0.f, 0.f};
    #pragma unroll
    for (int kb2 = 0; kb2 < 2; ++kb2) {
        bf16x8 kf[4];
        #pragma unroll
        for (int nj = 0; nj < 4; ++nj) {
            const int s = min((wave << 6) + (nj << 4) + lm, TT - 1);
            kf[nj] = *(const bf16x8*)(k + s * HD + (kb2 << 5) + (lk << 3));
        }
        #pragma unroll
        for (int mi = 0; mi < 4; ++mi)
            #pragma unroll
            for (int nj = 0; nj < 4; ++nj)
                acc[mi][nj] = __builtin_amdgcn_mfma_f32_16x16x32_bf16(qf[mi][kb2], kf[nj], acc[mi][nj], 0, 0, 0);
    }
    #pragma unroll
    for (int mi = 0; mi < 4; ++mi)
        #pragma unroll
        for (int nj = 0; nj < 4; ++nj)
            #pragma unroll
            for (int r = 0; r < 4; ++r) {
                const int m = (mi << 4) + (lk << 2) + r;
                const int s = (wave << 6) + (nj << 4) + lm;
                ST[m * 264 + s] = f2bf(acc[mi][nj][r] * 0.125f);
            }
    __syncthreads();

    // ---- Phase 2: softmax + blend (4 threads per row) ----
    {
        const int row = tid >> 2, part = tid & 3;
        const int trow = row0 + row;
        unsigned short* strow = ST + row * 264;
        if (trow < TT) {
            float mx = -1e30f;
            #pragma unroll
            for (int i = 0; i < 15; ++i) {
                const ushort4 u = *(const ushort4*)(strow + (part << 2) + (i << 4));
                mx = fmaxf(fmaxf(fmaxf(fmaxf(mx, b2f(u.x)), b2f(u.y)), b2f(u.z)), b2f(u.w));
            }
            if (part == 0)
                for (int s = 240; s < TT; ++s) mx = fmaxf(mx, b2f(strow[s]));
            mx = fmaxf(mx, __shfl_xor(mx, 1));
            mx = fmaxf(mx, __shfl_xor(mx, 2));
            float l = 0.f;
            #pragma unroll
            for (int i = 0; i < 15; ++i) {
                const int s0 = (part << 2) + (i << 4);
                const ushort4 u = *(const ushort4*)(strow + s0);
                const float e0 = __expf(b2f(u.x) - mx), e1 = __expf(b2f(u.y) - mx);
                const float e2 = __expf(b2f(u.z) - mx), e3 = __expf(b2f(u.w) - mx);
                l += (e0 + e1) + (e2 + e3);
                ushort4 o;
                o.x = f2bf(e0); o.y = f2bf(e1); o.z = f2bf(e2); o.w = f2bf(e3);
                *(ushort4*)(strow + s0) = o;
            }
            if (part == 0)
                for (int s = 240; s < TT; ++s) {
                    const float e = __expf(b2f(strow[s]) - mx);
                    l += e; strow[s] = f2bf(e);
                }
            l += __shfl_xor(l, 1);
            l += __shfl_xor(l, 2);
            const float sw = w / l, aw = 1.f - w;
            const float* amr = am + (size_t)trow * TT;
            #pragma unroll
            for (int i = 0; i < 15; ++i) {
                const int s0 = (part << 2) + (i << 4);
                const ushort4 u = *(const ushort4*)(strow + s0);
                const float a0 = amr[s0], a1 = amr[s0 + 1], a2 = amr[s0 + 2], a3 = amr[s0 + 3];
                ushort4 o;
                o.x = f2bf(b2f(u.x) * sw + aw * a0);
                o.y = f2bf(b2f(u.y) * sw + aw * a1);
                o.z = f2bf(b2f(u.z) * sw + aw * a2);
                o.w = f2bf(b2f(u.w) * sw + aw * a3);
                *(ushort4*)(strow + s0) = o;
            }
            if (part == 0) {
                for (int s = 240; s < TT; ++s)
                    strow[s] = f2bf(b2f(strow[s]) * sw + aw * amr[s]);
                for (int s = TT; s < 256; ++s) strow[s] = 0;
            }
        } else {
            #pragma unroll
            for (int i = 0; i < 16; ++i)
                *(ushort4*)(strow + (part << 2) + (i << 4)) = make_ushort4(0, 0, 0, 0);
        }
    }
    __syncthreads();

    // ---- Phase 3: O = P @ Vt (wave w -> rows 16w..16w+15), Vt from global ----
    f32x4 oacc[4];
    #pragma unroll
    for (int nj = 0; nj < 4; ++nj) oacc[nj] = (f32x4){0.f, 0.f, 0.f, 0.f};
    const unsigned short* strow3 = ST + ((wave << 4) + lm) * 264;
    const unsigned short* vtg = vt + ((size_t)bhj << 14);
    #pragma unroll 2
    for (int kb8 = 0; kb8 < 8; ++kb8) {
        const bf16x8 pf = *(const bf16x8*)(strow3 + (kb8 << 5) + (lk << 3));
        #pragma unroll
        for (int nj = 0; nj < 4; ++nj) {
            const int d = (nj << 4) + lm;
            const int chunk = (kb8 << 2) + lk;
            const bf16x8 vf = *(const bf16x8*)(vtg + (d << 8) + (chunk << 3));
            oacc[nj] = __builtin_amdgcn_mfma_f32_16x16x32_bf16(pf, vf, oacc[nj], 0, 0, 0);
        }
    }

    const int b = bhj / HJ;
    const int hj = bhj - b * HJ;
    const int h = hj / JJ;
    const int j = hj - h * JJ;
    #pragma unroll
    for (int r = 0; r < 4; ++r) {
        const int t = row0 + (wave << 4) + (lk << 2) + r;
        if (t < TT) {
            unsigned short* orow = ob + (((size_t)((b * TT + t) * JJ + j)) << 9) + (h << 6);
            #pragma unroll
            for (int nj = 0; nj < 4; ++nj)
                orow[(nj << 4) + lm] = f2bf(oacc[nj][r]);
        }
    }
}

// ---------------------------------------------------------------------------
// Kernel 3: bf16 MFMA GEMM  out = ob @ Wp + bias  (Wpt pre-transposed)
// ---------------------------------------------------------------------------
__global__ __launch_bounds__(256) void gemm_proj(
    const unsigned short* __restrict__ obb, const unsigned short* __restrict__ wt,
    const float* __restrict__ bias, float* __restrict__ out)
{
    __shared__ unsigned short As[128 * 32];
    __shared__ unsigned short Bs[128 * 32];
    __shared__ float Cp[4][16][68];
    const int tid = threadIdx.x;
    const int wave = tid >> 6, lane = tid & 63;
    const int m0 = blockIdx.y << 7, n0 = blockIdx.x << 7;
    const int wr = wave >> 1, wc = wave & 1;

    f32x4 acc[4][4];
    #pragma unroll
    for (int i = 0; i < 4; ++i)
        #pragma unroll
        for (int j = 0; j < 4; ++j) acc[i][j] = (f32x4){0.f, 0.f, 0.f, 0.f};

    const int srow = lane >> 2;
    const int sbyte = (lane & 3) << 4;
    const int arow0 = (wave << 5) + srow;
    const int arow1 = arow0 + 16;
    const size_t am0 = (size_t)min(m0 + arow0, MROWS - 1);
    const size_t am1 = (size_t)min(m0 + arow1, MROWS - 1);
    const char* ab = (const char*)obb;
    const char* wtb = (const char*)wt;
    char* Asb = (char*)As;
    char* Bsb = (char*)Bs;

    for (int k0 = 0; k0 < 512; k0 += 32) {
        __syncthreads();
        async16(ab + (am0 * 512 + k0) * 2 + sbyte, Asb + ((wave << 5) << 6));
        async16(ab + (am1 * 512 + k0) * 2 + sbyte, Asb + (((wave << 5) + 16) << 6));
        async16(wtb + ((size_t)(n0 + arow0) * 512 + k0) * 2 + sbyte, Bsb + ((wave << 5) << 6));
        async16(wtb + ((size_t)(n0 + arow1) * 512 + k0) * 2 + sbyte, Bsb + (((wave << 5) + 16) << 6));
        __syncthreads();
        bf16x8 af[4], bfr[4];
        #pragma unroll
        for (int i = 0; i < 4; ++i)
            af[i] = *(const bf16x8*)&As[((wr << 6) + (i << 4) + (lane & 15)) * 32 + ((lane >> 4) << 3)];
        #pragma unroll
        for (int j = 0; j < 4; ++j)
            bfr[j] = *(const bf16x8*)&Bs[((wc << 6) + (j << 4) + (lane & 15)) * 32 + ((lane >> 4) << 3)];
        #pragma unroll
        for (int i = 0; i < 4; ++i)
            #pragma unroll
            for (int j = 0; j < 4; ++j)
                acc[i][j] = __builtin_amdgcn_mfma_f32_16x16x32_bf16(af[i], bfr[j], acc[i][j], 0, 0, 0);
    }

    const int ch0 = lane & 15;
    const float4 bvec = *(const float4*)&bias[n0 + (wc << 6) + (ch0 << 2)];
    #pragma unroll
    for (int i = 0; i < 4; ++i) {
        #pragma unroll
        for (int j = 0; j < 4; ++j)
            #pragma unroll
            for (int r = 0; r < 4; ++r)
                Cp[wave][((lane >> 4) << 2) + r][(j << 4) + (lane & 15)] = acc[i][j][r];
        #pragma unroll
        for (int qq = 0; qq < 4; ++qq) {
            const int rr = (qq << 2) + (lane >> 4);
            const int ch = lane & 15;
            float4 val = *(const float4*)&Cp[wave][rr][ch << 2];
            const int m = m0 + (wr << 6) + (i << 4) + rr;
            if (m < MROWS) {
                val.x += bvec.x; val.y += bvec.y; val.z += bvec.z; val.w += bvec.w;
                *(float4*)(out + (size_t)m * 512 + n0 + (wc << 6) + (ch << 2)) = val;
            }
        }
    }
}

// ---------------------------------------------------------------------------
extern "C" void kernel_launch(void* const* d_in, const int* in_sizes, int n_in,
                              void* d_out, int out_size, void* d_ws, size_t ws_size,
                              hipStream_t stream)
{
    const float* x    = (const float*)d_in[0];
    const float* att  = (const float*)d_in[1];
    const float* wgt  = (const float*)d_in[2];
    const float* Wqkv = (const float*)d_in[3];
    const float* Wp   = (const float*)d_in[4];
    const float* bp   = (const float*)d_in[5];
    float* out = (float*)d_out;

    const size_t SZ = (size_t)MROWS * 512;        // 16,920,576
    unsigned short* xb    = (unsigned short*)d_ws;
    unsigned short* wqkvt = xb + SZ;
    unsigned short* wpt   = wqkvt + (size_t)1536 * 512;
    unsigned short* qb    = wpt + (size_t)512 * 512;
    unsigned short* kb    = qb + SZ;
    unsigned short* vb    = kb + SZ;
    unsigned short* ob    = vb + SZ;
    unsigned short* vtb   = ob + SZ;              // 1088*64*256 shorts (~35.7 MB)

    convert_x<<<4096, 256, 0, stream>>>(x, xb, (int)(SZ / 4));
    transpose_w<<<dim3(24, 8), 256, 0, stream>>>(Wqkv, wqkvt, 1536);
    transpose_w<<<dim3(8, 8), 256, 0, stream>>>(Wp, wpt, 512);

    gemm_qkv<<<dim3(12, 259), 256, 0, stream>>>(xb, wqkvt, qb, kb, vb);

    vtrans<<<dim3(1088), 256, 0, stream>>>(vb, vtb);

    attn_mfma<<<dim3(1088 * 4), 256, 0, stream>>>(qb, kb, vtb, att, wgt, ob);

    gemm_proj<<<dim3(4, 259), 256, 0, stream>>>(ob, wpt, bp, out);
}

// Round 2
// 617.869 us; speedup vs baseline: 1.0209x; 1.0209x over previous
//
#include <hip/hip_runtime.h>
#include <cstddef>
#include <cstdint>

#define NHEADS 8
#define TT 243
#define JJ 17
#define BB 8
#define CC 512
#define HD 64
#define MROWS 33048      // B*T*J
#define TJ 4131          // T*J
#define HJ 136           // H*J

typedef __attribute__((ext_vector_type(8))) short bf16x8;
typedef __attribute__((ext_vector_type(4))) float f32x4;

__device__ __forceinline__ unsigned short f2bf(float f) {
    unsigned u = __float_as_uint(f);
    unsigned r = (u + 0x7fff + ((u >> 16) & 1)) >> 16;   // RNE
    return (unsigned short)r;
}
__device__ __forceinline__ float b2f(unsigned short u) {
    return __uint_as_float(((unsigned)u) << 16);
}
__device__ __forceinline__ void async16(const void* g, void* l) {
    __builtin_amdgcn_global_load_lds(
        (const __attribute__((address_space(1))) void*)g,
        (__attribute__((address_space(3))) void*)l, 16, 0, 0);
}

// ---------------------------------------------------------------------------
// prep: x fp32 -> bf16 (same layout)
// ---------------------------------------------------------------------------
__global__ __launch_bounds__(256) void convert_x(
    const float* __restrict__ in, unsigned short* __restrict__ out, int n4)
{
    for (int i = blockIdx.x * 256 + threadIdx.x; i < n4; i += gridDim.x * 256) {
        const float4 v = *(const float4*)(in + (size_t)i * 4);
        ushort4 o;
        o.x = f2bf(v.x); o.y = f2bf(v.y); o.z = f2bf(v.z); o.w = f2bf(v.w);
        *(ushort4*)(out + (size_t)i * 4) = o;
    }
}

// ---------------------------------------------------------------------------
// prep: W fp32 [512][N] -> bf16 [N][512]  (transpose + convert)
// ---------------------------------------------------------------------------
__global__ __launch_bounds__(256) void transpose_w(
    const float* __restrict__ src, unsigned short* __restrict__ dst, int N)
{
    __shared__ unsigned short tile[64][65];
    const int tid = threadIdx.x;
    const int c = tid & 63, r4 = tid >> 6;
    const int n0 = blockIdx.x << 6, k0 = blockIdx.y << 6;
    #pragma unroll
    for (int p = 0; p < 16; ++p) {
        const int r = (p << 2) + r4;
        tile[r][c] = f2bf(src[(size_t)(k0 + r) * N + n0 + c]);
    }
    __syncthreads();
    #pragma unroll
    for (int p = 0; p < 16; ++p) {
        const int rr = (p << 2) + r4;
        dst[(size_t)(n0 + rr) * 512 + k0 + c] = tile[c][rr];
    }
}

// ---------------------------------------------------------------------------
// Kernel 1: bf16 MFMA GEMM  qkv = xb @ Wqkv  (Wqkvt pre-transposed [1536][512])
// ---------------------------------------------------------------------------
__global__ __launch_bounds__(256) void gemm_qkv(
    const unsigned short* __restrict__ xb, const unsigned short* __restrict__ wt,
    unsigned short* __restrict__ qb, unsigned short* __restrict__ kb,
    unsigned short* __restrict__ vb)
{
    __shared__ unsigned short As[128 * 32];
    __shared__ unsigned short Bs[128 * 32];
    __shared__ unsigned short Cq[4][16][72];
    const int tid = threadIdx.x;
    const int wave = tid >> 6, lane = tid & 63;
    const int m0 = blockIdx.y << 7, n0 = blockIdx.x << 7;
    const int wr = wave >> 1, wc = wave & 1;

    f32x4 acc[4][4];
    #pragma unroll
    for (int i = 0; i < 4; ++i)
        #pragma unroll
        for (int j = 0; j < 4; ++j) acc[i][j] = (f32x4){0.f, 0.f, 0.f, 0.f};

    const int srow = lane >> 2;
    const int sbyte = (lane & 3) << 4;
    const int arow0 = (wave << 5) + srow;
    const int arow1 = arow0 + 16;
    const size_t am0 = (size_t)min(m0 + arow0, MROWS - 1);
    const size_t am1 = (size_t)min(m0 + arow1, MROWS - 1);
    const char* xbb = (const char*)xb;
    const char* wtb = (const char*)wt;
    char* Asb = (char*)As;
    char* Bsb = (char*)Bs;

    for (int k0 = 0; k0 < 512; k0 += 32) {
        __syncthreads();
        async16(xbb + (am0 * 512 + k0) * 2 + sbyte, Asb + ((wave << 5) << 6));
        async16(xbb + (am1 * 512 + k0) * 2 + sbyte, Asb + (((wave << 5) + 16) << 6));
        async16(wtb + ((size_t)(n0 + arow0) * 512 + k0) * 2 + sbyte, Bsb + ((wave << 5) << 6));
        async16(wtb + ((size_t)(n0 + arow1) * 512 + k0) * 2 + sbyte, Bsb + (((wave << 5) + 16) << 6));
        __syncthreads();
        bf16x8 af[4], bfr[4];
        #pragma unroll
        for (int i = 0; i < 4; ++i)
            af[i] = *(const bf16x8*)&As[((wr << 6) + (i << 4) + (lane & 15)) * 32 + ((lane >> 4) << 3)];
        #pragma unroll
        for (int j = 0; j < 4; ++j)
            bfr[j] = *(const bf16x8*)&Bs[((wc << 6) + (j << 4) + (lane & 15)) * 32 + ((lane >> 4) << 3)];
        #pragma unroll
        for (int i = 0; i < 4; ++i)
            #pragma unroll
            for (int j = 0; j < 4; ++j)
                acc[i][j] = __builtin_amdgcn_mfma_f32_16x16x32_bf16(af[i], bfr[j], acc[i][j], 0, 0, 0);
    }

    const int nw = n0 + (wc << 6);
    const int which = nw >> 9;
    const int h = (nw >> 6) & 7;
    unsigned short* const dst = which == 0 ? qb : (which == 1 ? kb : vb);
    #pragma unroll
    for (int i = 0; i < 4; ++i) {
        #pragma unroll
        for (int j = 0; j < 4; ++j)
            #pragma unroll
            for (int r = 0; r < 4; ++r)
                Cq[wave][((lane >> 4) << 2) + r][(j << 4) + (lane & 15)] = f2bf(acc[i][j][r]);
        #pragma unroll
        for (int qq = 0; qq < 4; ++qq) {
            const int rr = (qq << 2) + (lane >> 4);
            const int ch = lane & 15;
            const ushort4 val = *(const ushort4*)&Cq[wave][rr][ch << 2];
            const int m = m0 + (wr << 6) + (i << 4) + rr;
            if (m < MROWS) {
                const int b = m / TJ; const int rm = m - b * TJ;
                const int t = rm / JJ; const int jj = rm - t * JJ;
                const size_t base = (((size_t)((b * NHEADS + h) * JJ + jj) * TT + t) << 6) + (ch << 2);
                *(ushort4*)(dst + base) = val;
            }
        }
    }
}

// ---------------------------------------------------------------------------
// vtrans: vb [bhj][t][64] -> vt [bhj][64][256] (d-major, zero-padded t,
// LINEAR layout — consumed straight from global/L2 by attn phase 3)
// ---------------------------------------------------------------------------
__global__ __launch_bounds__(256) void vtrans(
    const unsigned short* __restrict__ vb, unsigned short* __restrict__ vt)
{
    __shared__ unsigned short TL[64 * 264];
    const int tid = threadIdx.x;
    const int bhj = blockIdx.x;
    const unsigned short* src = vb + (size_t)bhj * TT * HD;

    {   // zero cols 240..255 (covers the t>=243 padding; 240..242 rewritten)
        const int d = tid >> 2, qq = tid & 3;
        *(ushort4*)(TL + d * 264 + 240 + (qq << 2)) = make_ushort4(0, 0, 0, 0);
    }
    __syncthreads();
    #pragma unroll
    for (int p = 0; p < 16; ++p) {
        const int idxq = tid + (p << 8);
        const int t = idxq >> 4;
        if (t < TT) {
            const int d0 = (idxq & 15) << 2;
            const ushort4 u = *(const ushort4*)(src + t * HD + d0);
            TL[(d0 + 0) * 264 + t] = u.x;
            TL[(d0 + 1) * 264 + t] = u.y;
            TL[(d0 + 2) * 264 + t] = u.z;
            TL[(d0 + 3) * 264 + t] = u.w;
        }
    }
    __syncthreads();
    unsigned short* dst = vt + ((size_t)bhj << 14);
    #pragma unroll
    for (int p = 0; p < 8; ++p) {
        const int cw = tid + (p << 8);           // 2048 chunk-writes
        const int d = cw >> 5, c = cw & 31;
        const ushort4 a = *(const ushort4*)(TL + d * 264 + (c << 3));
        const ushort4 bq = *(const ushort4*)(TL + d * 264 + (c << 3) + 4);
        *(ushort4*)(dst + (d << 8) + (c << 3)) = a;
        *(ushort4*)(dst + (d << 8) + (c << 3) + 4) = bq;
    }
}

// ---------------------------------------------------------------------------
// Kernel 2: MFMA attention. block = (bhj, 64-row tile), 4 waves.
// Phase1: wave w computes S[:, 64w..64w+64) = Q K^T via 16x16x32 mfma.
// Phase2: att_map loads HOISTED into registers at phase top (60/thread,
//         all outstanding) so their HBM latency hides under max+exp passes;
//         then row-parallel softmax + blend over row-major bf16 S in LDS.
// Phase3: O = P @ Vt, Vt read directly from global (L2/L3-resident).
// ---------------------------------------------------------------------------
__global__ __launch_bounds__(256, 4) void attn_mfma(
    const unsigned short* __restrict__ qb, const unsigned short* __restrict__ kb,
    const unsigned short* __restrict__ vt, const float* __restrict__ att,
    const float* __restrict__ wptr, unsigned short* __restrict__ ob)
{
    __shared__ unsigned short ST[64 * 264];   // S / P, row-major bf16

    const int tid = threadIdx.x;
    const int wave = tid >> 6, lane = tid & 63;
    const int tile = blockIdx.x & 3, bhj = blockIdx.x >> 2;
    const int row0 = tile << 6;

    const unsigned short* q = qb + (size_t)bhj * TT * HD;
    const unsigned short* k = kb + (size_t)bhj * TT * HD;
    const float* am = att + (size_t)bhj * TT * TT;
    const float w = wptr[0];

    // ---- Phase 1 ----
    const int lm = lane & 15, lk = lane >> 4;
    bf16x8 qf[4][2];
    #pragma unroll
    for (int mi = 0; mi < 4; ++mi) {
        const int r = min(row0 + (mi << 4) + lm, TT - 1);
        #pragma unroll
        for (int kb2 = 0; kb2 < 2; ++kb2)
            qf[mi][kb2] = *(const bf16x8*)(q + r * HD + (kb2 << 5) + (lk << 3));
    }
    f32x4 acc[4][4];
    #pragma unroll
    for (int mi = 0; mi < 4; ++mi)
        #pragma unroll
        for (int nj = 0; nj < 4; ++nj) acc[mi][nj] = (f32x4){0.f, 0.f, 0.f, 0.f};
    #pragma unroll
    for (int kb2 = 0; kb2 < 2; ++kb2) {
        bf16x8 kf[4];
        #pragma unroll
        for (int nj = 0; nj < 4; ++nj) {
            const int s = min((wave << 6) + (nj << 4) + lm, TT - 1);
            kf[nj] = *(const bf16x8*)(k + s * HD + (kb2 << 5) + (lk << 3));
        }
        #pragma unroll
        for (int mi = 0; mi < 4; ++mi)
            #pragma unroll
            for (int nj = 0; nj < 4; ++nj)
                acc[mi][nj] = __builtin_amdgcn_mfma_f32_16x16x32_bf16(qf[mi][kb2], kf[nj], acc[mi][nj], 0, 0, 0);
    }
    #pragma unroll
    for (int mi = 0; mi < 4; ++mi)
        #pragma unroll
        for (int nj = 0; nj < 4; ++nj)
            #pragma unroll
            for (int r = 0; r < 4; ++r) {
                const int m = (mi << 4) + (lk << 2) + r;
                const int s = (wave << 6) + (nj << 4) + lm;
                ST[m * 264 + s] = f2bf(acc[mi][nj][r] * 0.125f);
            }
    __syncthreads();

    // ---- Phase 2: softmax + blend (4 threads per row) ----
    {
        const int row = tid >> 2, part = tid & 3;
        const int trow = row0 + row;
        unsigned short* strow = ST + row * 264;
        if (trow < TT) {
            const float* amr = am + (size_t)trow * TT;

            // hoisted att_map loads: all 60 (+3 tail) issued up front so the
            // HBM latency hides under the max/exp passes below
            float areg[15][4];
            #pragma unroll
            for (int i = 0; i < 15; ++i) {
                const int s0 = (part << 2) + (i << 4);
                areg[i][0] = amr[s0 + 0];
                areg[i][1] = amr[s0 + 1];
                areg[i][2] = amr[s0 + 2];
                areg[i][3] = amr[s0 + 3];
            }
            float at0 = 0.f, at1 = 0.f, at2 = 0.f;
            if (part == 0) { at0 = amr[240]; at1 = amr[241]; at2 = amr[242]; }

            float mx = -1e30f;
            #pragma unroll
            for (int i = 0; i < 15; ++i) {
                const ushort4 u = *(const ushort4*)(strow + (part << 2) + (i << 4));
                mx = fmaxf(fmaxf(fmaxf(fmaxf(mx, b2f(u.x)), b2f(u.y)), b2f(u.z)), b2f(u.w));
            }
            if (part == 0)
                for (int s = 240; s < TT; ++s) mx = fmaxf(mx, b2f(strow[s]));
            mx = fmaxf(mx, __shfl_xor(mx, 1));
            mx = fmaxf(mx, __shfl_xor(mx, 2));
            float l = 0.f;
            #pragma unroll
            for (int i = 0; i < 15; ++i) {
                const int s0 = (part << 2) + (i << 4);
                const ushort4 u = *(const ushort4*)(strow + s0);
                const float e0 = __expf(b2f(u.x) - mx), e1 = __expf(b2f(u.y) - mx);
                const float e2 = __expf(b2f(u.z) - mx), e3 = __expf(b2f(u.w) - mx);
                l += (e0 + e1) + (e2 + e3);
                ushort4 o;
                o.x = f2bf(e0); o.y = f2bf(e1); o.z = f2bf(e2); o.w = f2bf(e3);
                *(ushort4*)(strow + s0) = o;
            }
            if (part == 0)
                for (int s = 240; s < TT; ++s) {
                    const float e = __expf(b2f(strow[s]) - mx);
                    l += e; strow[s] = f2bf(e);
                }
            l += __shfl_xor(l, 1);
            l += __shfl_xor(l, 2);
            const float sw = w / l, aw = 1.f - w;
            #pragma unroll
            for (int i = 0; i < 15; ++i) {
                const int s0 = (part << 2) + (i << 4);
                const ushort4 u = *(const ushort4*)(strow + s0);
                ushort4 o;
                o.x = f2bf(b2f(u.x) * sw + aw * areg[i][0]);
                o.y = f2bf(b2f(u.y) * sw + aw * areg[i][1]);
                o.z = f2bf(b2f(u.z) * sw + aw * areg[i][2]);
                o.w = f2bf(b2f(u.w) * sw + aw * areg[i][3]);
                *(ushort4*)(strow + s0) = o;
            }
            if (part == 0) {
                strow[240] = f2bf(b2f(strow[240]) * sw + aw * at0);
                strow[241] = f2bf(b2f(strow[241]) * sw + aw * at1);
                strow[242] = f2bf(b2f(strow[242]) * sw + aw * at2);
                for (int s = TT; s < 256; ++s) strow[s] = 0;
            }
        } else {
            #pragma unroll
            for (int i = 0; i < 16; ++i)
                *(ushort4*)(strow + (part << 2) + (i << 4)) = make_ushort4(0, 0, 0, 0);
        }
    }
    __syncthreads();

    // ---- Phase 3: O = P @ Vt (wave w -> rows 16w..16w+15), Vt from global ----
    f32x4 oacc[4];
    #pragma unroll
    for (int nj = 0; nj < 4; ++nj) oacc[nj] = (f32x4){0.f, 0.f, 0.f, 0.f};
    const unsigned short* strow3 = ST + ((wave << 4) + lm) * 264;
    const unsigned short* vtg = vt + ((size_t)bhj << 14);
    #pragma unroll 2
    for (int kb8 = 0; kb8 < 8; ++kb8) {
        const bf16x8 pf = *(const bf16x8*)(strow3 + (kb8 << 5) + (lk << 3));
        #pragma unroll
        for (int nj = 0; nj < 4; ++nj) {
            const int d = (nj << 4) + lm;
            const int chunk = (kb8 << 2) + lk;
            const bf16x8 vf = *(const bf16x8*)(vtg + (d << 8) + (chunk << 3));
            oacc[nj] = __builtin_amdgcn_mfma_f32_16x16x32_bf16(pf, vf, oacc[nj], 0, 0, 0);
        }
    }

    const int b = bhj / HJ;
    const int hj = bhj - b * HJ;
    const int h = hj / JJ;
    const int j = hj - h * JJ;
    #pragma unroll
    for (int r = 0; r < 4; ++r) {
        const int t = row0 + (wave << 4) + (lk << 2) + r;
        if (t < TT) {
            unsigned short* orow = ob + (((size_t)((b * TT + t) * JJ + j)) << 9) + (h << 6);
            #pragma unroll
            for (int nj = 0; nj < 4; ++nj)
                orow[(nj << 4) + lm] = f2bf(oacc[nj][r]);
        }
    }
}

// ---------------------------------------------------------------------------
// Kernel 3: bf16 MFMA GEMM  out = ob @ Wp + bias  (Wpt pre-transposed)
// ---------------------------------------------------------------------------
__global__ __launch_bounds__(256) void gemm_proj(
    const unsigned short* __restrict__ obb, const unsigned short* __restrict__ wt,
    const float* __restrict__ bias, float* __restrict__ out)
{
    __shared__ unsigned short As[128 * 32];
    __shared__ unsigned short Bs[128 * 32];
    __shared__ float Cp[4][16][68];
    const int tid = threadIdx.x;
    const int wave = tid >> 6, lane = tid & 63;
    const int m0 = blockIdx.y << 7, n0 = blockIdx.x << 7;
    const int wr = wave >> 1, wc = wave & 1;

    f32x4 acc[4][4];
    #pragma unroll
    for (int i = 0; i < 4; ++i)
        #pragma unroll
        for (int j = 0; j < 4; ++j) acc[i][j] = (f32x4){0.f, 0.f, 0.f, 0.f};

    const int srow = lane >> 2;
    const int sbyte = (lane & 3) << 4;
    const int arow0 = (wave << 5) + srow;
    const int arow1 = arow0 + 16;
    const size_t am0 = (size_t)min(m0 + arow0, MROWS - 1);
    const size_t am1 = (size_t)min(m0 + arow1, MROWS - 1);
    const char* ab = (const char*)obb;
    const char* wtb = (const char*)wt;
    char* Asb = (char*)As;
    char* Bsb = (char*)Bs;

    for (int k0 = 0; k0 < 512; k0 += 32) {
        __syncthreads();
        async16(ab + (am0 * 512 + k0) * 2 + sbyte, Asb + ((wave << 5) << 6));
        async16(ab + (am1 * 512 + k0) * 2 + sbyte, Asb + (((wave << 5) + 16) << 6));
        async16(wtb + ((size_t)(n0 + arow0) * 512 + k0) * 2 + sbyte, Bsb + ((wave << 5) << 6));
        async16(wtb + ((size_t)(n0 + arow1) * 512 + k0) * 2 + sbyte, Bsb + (((wave << 5) + 16) << 6));
        __syncthreads();
        bf16x8 af[4], bfr[4];
        #pragma unroll
        for (int i = 0; i < 4; ++i)
            af[i] = *(const bf16x8*)&As[((wr << 6) + (i << 4) + (lane & 15)) * 32 + ((lane >> 4) << 3)];
        #pragma unroll
        for (int j = 0; j < 4; ++j)
            bfr[j] = *(const bf16x8*)&Bs[((wc << 6) + (j << 4) + (lane & 15)) * 32 + ((lane >> 4) << 3)];
        #pragma unroll
        for (int i = 0; i < 4; ++i)
            #pragma unroll
            for (int j = 0; j < 4; ++j)
                acc[i][j] = __builtin_amdgcn_mfma_f32_16x16x32_bf16(af[i], bfr[j], acc[i][j], 0, 0, 0);
    }

    const int ch0 = lane & 15;
    const float4 bvec = *(const float4*)&bias[n0 + (wc << 6) + (ch0 << 2)];
    #pragma unroll
    for (int i = 0; i < 4; ++i) {
        #pragma unroll
        for (int j = 0; j < 4; ++j)
            #pragma unroll
            for (int r = 0; r < 4; ++r)
                Cp[wave][((lane >> 4) << 2) + r][(j << 4) + (lane & 15)] = acc[i][j][r];
        #pragma unroll
        for (int qq = 0; qq < 4; ++qq) {
            const int rr = (qq << 2) + (lane >> 4);
            const int ch = lane & 15;
            float4 val = *(const float4*)&Cp[wave][rr][ch << 2];
            const int m = m0 + (wr << 6) + (i << 4) + rr;
            if (m < MROWS) {
                val.x += bvec.x; val.y += bvec.y; val.z += bvec.z; val.w += bvec.w;
                *(float4*)(out + (size_t)m * 512 + n0 + (wc << 6) + (ch << 2)) = val;
            }
        }
    }
}

// ---------------------------------------------------------------------------
extern "C" void kernel_launch(void* const* d_in, const int* in_sizes, int n_in,
                              void* d_out, int out_size, void* d_ws, size_t ws_size,
                              hipStream_t stream)
{
    const float* x    = (const float*)d_in[0];
    const float* att  = (const float*)d_in[1];
    const float* wgt  = (const float*)d_in[2];
    const float* Wqkv = (const float*)d_in[3];
    const float* Wp   = (const float*)d_in[4];
    const float* bp   = (const float*)d_in[5];
    float* out = (float*)d_out;

    const size_t SZ = (size_t)MROWS * 512;        // 16,920,576
    unsigned short* xb    = (unsigned short*)d_ws;
    unsigned short* wqkvt = xb + SZ;
    unsigned short* wpt   = wqkvt + (size_t)1536 * 512;
    unsigned short* qb    = wpt + (size_t)512 * 512;
    unsigned short* kb    = qb + SZ;
    unsigned short* vb    = kb + SZ;
    unsigned short* ob    = vb + SZ;
    unsigned short* vtb   = ob + SZ;              // 1088*64*256 shorts (~35.7 MB)

    convert_x<<<4096, 256, 0, stream>>>(x, xb, (int)(SZ / 4));
    transpose_w<<<dim3(24, 8), 256, 0, stream>>>(Wqkv, wqkvt, 1536);
    transpose_w<<<dim3(8, 8), 256, 0, stream>>>(Wp, wpt, 512);

    gemm_qkv<<<dim3(12, 259), 256, 0, stream>>>(xb, wqkvt, qb, kb, vb);

    vtrans<<<dim3(1088), 256, 0, stream>>>(vb, vtb);

    attn_mfma<<<dim3(1088 * 4), 256, 0, stream>>>(qb, kb, vtb, att, wgt, ob);

    gemm_proj<<<dim3(4, 259), 256, 0, stream>>>(ob, wpt, bp, out);
}

// Round 3
// 600.073 us; speedup vs baseline: 1.0512x; 1.0297x over previous
//
#include <hip/hip_runtime.h>
#include <cstddef>
#include <cstdint>

#define NHEADS 8
#define TT 243
#define JJ 17
#define BB 8
#define CC 512
#define HD 64
#define MROWS 33048      // B*T*J
#define TJ 4131          // T*J
#define HJ 136           // H*J

typedef __attribute__((ext_vector_type(8))) short bf16x8;
typedef __attribute__((ext_vector_type(4))) float f32x4;

__device__ __forceinline__ unsigned short f2bf(float f) {
    unsigned u = __float_as_uint(f);
    unsigned r = (u + 0x7fff + ((u >> 16) & 1)) >> 16;   // RNE
    return (unsigned short)r;
}
__device__ __forceinline__ float b2f(unsigned short u) {
    return __uint_as_float(((unsigned)u) << 16);
}
__device__ __forceinline__ void async16(const void* g, void* l) {
    __builtin_amdgcn_global_load_lds(
        (const __attribute__((address_space(1))) void*)g,
        (__attribute__((address_space(3))) void*)l, 16, 0, 0);
}

// ---------------------------------------------------------------------------
// prep: x fp32 -> bf16 (same layout)
// ---------------------------------------------------------------------------
__global__ __launch_bounds__(256) void convert_x(
    const float* __restrict__ in, unsigned short* __restrict__ out, int n4)
{
    for (int i = blockIdx.x * 256 + threadIdx.x; i < n4; i += gridDim.x * 256) {
        const float4 v = *(const float4*)(in + (size_t)i * 4);
        ushort4 o;
        o.x = f2bf(v.x); o.y = f2bf(v.y); o.z = f2bf(v.z); o.w = f2bf(v.w);
        *(ushort4*)(out + (size_t)i * 4) = o;
    }
}

// ---------------------------------------------------------------------------
// prep: W fp32 [512][N] -> bf16 [N][512]  (transpose + convert)
// ---------------------------------------------------------------------------
__global__ __launch_bounds__(256) void transpose_w(
    const float* __restrict__ src, unsigned short* __restrict__ dst, int N)
{
    __shared__ unsigned short tile[64][65];
    const int tid = threadIdx.x;
    const int c = tid & 63, r4 = tid >> 6;
    const int n0 = blockIdx.x << 6, k0 = blockIdx.y << 6;
    #pragma unroll
    for (int p = 0; p < 16; ++p) {
        const int r = (p << 2) + r4;
        tile[r][c] = f2bf(src[(size_t)(k0 + r) * N + n0 + c]);
    }
    __syncthreads();
    #pragma unroll
    for (int p = 0; p < 16; ++p) {
        const int rr = (p << 2) + r4;
        dst[(size_t)(n0 + rr) * 512 + k0 + c] = tile[c][rr];
    }
}

// ---------------------------------------------------------------------------
// Kernel 1: bf16 MFMA GEMM  qkv = xb @ Wqkv  (Wqkvt pre-transposed [1536][512])
// Double-buffered LDS (2-phase): stage next K-tile while computing current.
// One barrier per K-step. Epilogue scratch aliases the dead staging buffers.
// ---------------------------------------------------------------------------
__global__ __launch_bounds__(256) void gemm_qkv(
    const unsigned short* __restrict__ xb, const unsigned short* __restrict__ wt,
    unsigned short* __restrict__ qb, unsigned short* __restrict__ kb,
    unsigned short* __restrict__ vb)
{
    __shared__ __align__(16) char smem[32768];   // A0|A1|B0|B1, 8KB each
    char* const A0 = smem;
    char* const A1 = smem + 8192;
    char* const B0 = smem + 16384;
    char* const B1 = smem + 24576;

    const int tid = threadIdx.x;
    const int wave = tid >> 6, lane = tid & 63;
    const int m0 = blockIdx.y << 7, n0 = blockIdx.x << 7;
    const int wr = wave >> 1, wc = wave & 1;

    f32x4 acc[4][4];
    #pragma unroll
    for (int i = 0; i < 4; ++i)
        #pragma unroll
        for (int j = 0; j < 4; ++j) acc[i][j] = (f32x4){0.f, 0.f, 0.f, 0.f};

    const int srow = lane >> 2;
    const int sbyte = (lane & 3) << 4;
    const int arow0 = (wave << 5) + srow;
    const int arow1 = arow0 + 16;
    const size_t am0 = (size_t)min(m0 + arow0, MROWS - 1);
    const size_t am1 = (size_t)min(m0 + arow1, MROWS - 1);
    const char* xbb = (const char*)xb;
    const char* wtb = (const char*)wt;

#define STAGEQ(Ad, Bd, k0) do { \
    async16(xbb + (am0 * 512 + (k0)) * 2 + sbyte, (Ad) + ((wave << 5) << 6)); \
    async16(xbb + (am1 * 512 + (k0)) * 2 + sbyte, (Ad) + (((wave << 5) + 16) << 6)); \
    async16(wtb + ((size_t)(n0 + arow0) * 512 + (k0)) * 2 + sbyte, (Bd) + ((wave << 5) << 6)); \
    async16(wtb + ((size_t)(n0 + arow1) * 512 + (k0)) * 2 + sbyte, (Bd) + (((wave << 5) + 16) << 6)); \
} while (0)

#define COMPUTEQ(Ap, Bp) do { \
    bf16x8 af[4], bfr[4]; \
    _Pragma("unroll") \
    for (int i = 0; i < 4; ++i) \
        af[i] = *(const bf16x8*)((const unsigned short*)(Ap) + \
            ((wr << 6) + (i << 4) + (lane & 15)) * 32 + ((lane >> 4) << 3)); \
    _Pragma("unroll") \
    for (int j = 0; j < 4; ++j) \
        bfr[j] = *(const bf16x8*)((const unsigned short*)(Bp) + \
            ((wc << 6) + (j << 4) + (lane & 15)) * 32 + ((lane >> 4) << 3)); \
    _Pragma("unroll") \
    for (int i = 0; i < 4; ++i) \
        _Pragma("unroll") \
        for (int j = 0; j < 4; ++j) \
            acc[i][j] = __builtin_amdgcn_mfma_f32_16x16x32_bf16(af[i], bfr[j], acc[i][j], 0, 0, 0); \
} while (0)

    STAGEQ(A0, B0, 0);
    __syncthreads();
    #pragma unroll
    for (int t = 0; t < 16; t += 2) {
        STAGEQ(A1, B1, (t + 1) << 5);
        COMPUTEQ(A0, B0);
        __syncthreads();                    // drains vmcnt (A1/B1 stage) + lgkm
        if (t + 2 < 16) STAGEQ(A0, B0, (t + 2) << 5);
        COMPUTEQ(A1, B1);
        __syncthreads();
    }
#undef STAGEQ
#undef COMPUTEQ

    // epilogue scratch aliases staging buffers (dead after final barrier)
    unsigned short (*Cq)[16][72] = (unsigned short (*)[16][72])smem;

    const int nw = n0 + (wc << 6);
    const int which = nw >> 9;
    const int h = (nw >> 6) & 7;
    unsigned short* const dst = which == 0 ? qb : (which == 1 ? kb : vb);
    #pragma unroll
    for (int i = 0; i < 4; ++i) {
        #pragma unroll
        for (int j = 0; j < 4; ++j)
            #pragma unroll
            for (int r = 0; r < 4; ++r)
                Cq[wave][((lane >> 4) << 2) + r][(j << 4) + (lane & 15)] = f2bf(acc[i][j][r]);
        #pragma unroll
        for (int qq = 0; qq < 4; ++qq) {
            const int rr = (qq << 2) + (lane >> 4);
            const int ch = lane & 15;
            const ushort4 val = *(const ushort4*)&Cq[wave][rr][ch << 2];
            const int m = m0 + (wr << 6) + (i << 4) + rr;
            if (m < MROWS) {
                const int b = m / TJ; const int rm = m - b * TJ;
                const int t = rm / JJ; const int jj = rm - t * JJ;
                const size_t base = (((size_t)((b * NHEADS + h) * JJ + jj) * TT + t) << 6) + (ch << 2);
                *(ushort4*)(dst + base) = val;
            }
        }
    }
}

// ---------------------------------------------------------------------------
// vtrans: vb [bhj][t][64] -> vt [bhj][64][256] (d-major, zero-padded t,
// LINEAR layout — consumed straight from global/L2 by attn phase 3)
// ---------------------------------------------------------------------------
__global__ __launch_bounds__(256) void vtrans(
    const unsigned short* __restrict__ vb, unsigned short* __restrict__ vt)
{
    __shared__ unsigned short TL[64 * 264];
    const int tid = threadIdx.x;
    const int bhj = blockIdx.x;
    const unsigned short* src = vb + (size_t)bhj * TT * HD;

    {   // zero cols 240..255 (covers the t>=243 padding; 240..242 rewritten)
        const int d = tid >> 2, qq = tid & 3;
        *(ushort4*)(TL + d * 264 + 240 + (qq << 2)) = make_ushort4(0, 0, 0, 0);
    }
    __syncthreads();
    #pragma unroll
    for (int p = 0; p < 16; ++p) {
        const int idxq = tid + (p << 8);
        const int t = idxq >> 4;
        if (t < TT) {
            const int d0 = (idxq & 15) << 2;
            const ushort4 u = *(const ushort4*)(src + t * HD + d0);
            TL[(d0 + 0) * 264 + t] = u.x;
            TL[(d0 + 1) * 264 + t] = u.y;
            TL[(d0 + 2) * 264 + t] = u.z;
            TL[(d0 + 3) * 264 + t] = u.w;
        }
    }
    __syncthreads();
    unsigned short* dst = vt + ((size_t)bhj << 14);
    #pragma unroll
    for (int p = 0; p < 8; ++p) {
        const int cw = tid + (p << 8);           // 2048 chunk-writes
        const int d = cw >> 5, c = cw & 31;
        const ushort4 a = *(const ushort4*)(TL + d * 264 + (c << 3));
        const ushort4 bq = *(const ushort4*)(TL + d * 264 + (c << 3) + 4);
        *(ushort4*)(dst + (d << 8) + (c << 3)) = a;
        *(ushort4*)(dst + (d << 8) + (c << 3) + 4) = bq;
    }
}

// ---------------------------------------------------------------------------
// Kernel 2: MFMA attention. block = (bhj, 64-row tile), 4 waves.
// Phase1: wave w computes S[:, 64w..64w+64) = Q K^T via 16x16x32 mfma.
// Phase2: att_map loads HOISTED into registers at phase top (60/thread,
//         all outstanding) so their HBM latency hides under max+exp passes;
//         then row-parallel softmax + blend over row-major bf16 S in LDS.
// Phase3: O = P @ Vt, Vt read directly from global (L2/L3-resident).
// ---------------------------------------------------------------------------
__global__ __launch_bounds__(256, 4) void attn_mfma(
    const unsigned short* __restrict__ qb, const unsigned short* __restrict__ kb,
    const unsigned short* __restrict__ vt, const float* __restrict__ att,
    const float* __restrict__ wptr, unsigned short* __restrict__ ob)
{
    __shared__ unsigned short ST[64 * 264];   // S / P, row-major bf16

    const int tid = threadIdx.x;
    const int wave = tid >> 6, lane = tid & 63;
    const int tile = blockIdx.x & 3, bhj = blockIdx.x >> 2;
    const int row0 = tile << 6;

    const unsigned short* q = qb + (size_t)bhj * TT * HD;
    const unsigned short* k = kb + (size_t)bhj * TT * HD;
    const float* am = att + (size_t)bhj * TT * TT;
    const float w = wptr[0];

    // ---- Phase 1 ----
    const int lm = lane & 15, lk = lane >> 4;
    bf16x8 qf[4][2];
    #pragma unroll
    for (int mi = 0; mi < 4; ++mi) {
        const int r = min(row0 + (mi << 4) + lm, TT - 1);
        #pragma unroll
        for (int kb2 = 0; kb2 < 2; ++kb2)
            qf[mi][kb2] = *(const bf16x8*)(q + r * HD + (kb2 << 5) + (lk << 3));
    }
    f32x4 acc[4][4];
    #pragma unroll
    for (int mi = 0; mi < 4; ++mi)
        #pragma unroll
        for (int nj = 0; nj < 4; ++nj) acc[mi][nj] = (f32x4){0.f, 0.f, 0.f, 0.f};
    #pragma unroll
    for (int kb2 = 0; kb2 < 2; ++kb2) {
        bf16x8 kf[4];
        #pragma unroll
        for (int nj = 0; nj < 4; ++nj) {
            const int s = min((wave << 6) + (nj << 4) + lm, TT - 1);
            kf[nj] = *(const bf16x8*)(k + s * HD + (kb2 << 5) + (lk << 3));
        }
        #pragma unroll
        for (int mi = 0; mi < 4; ++mi)
            #pragma unroll
            for (int nj = 0; nj < 4; ++nj)
                acc[mi][nj] = __builtin_amdgcn_mfma_f32_16x16x32_bf16(qf[mi][kb2], kf[nj], acc[mi][nj], 0, 0, 0);
    }
    #pragma unroll
    for (int mi = 0; mi < 4; ++mi)
        #pragma unroll
        for (int nj = 0; nj < 4; ++nj)
            #pragma unroll
            for (int r = 0; r < 4; ++r) {
                const int m = (mi << 4) + (lk << 2) + r;
                const int s = (wave << 6) + (nj << 4) + lm;
                ST[m * 264 + s] = f2bf(acc[mi][nj][r] * 0.125f);
            }
    __syncthreads();

    // ---- Phase 2: softmax + blend (4 threads per row) ----
    {
        const int row = tid >> 2, part = tid & 3;
        const int trow = row0 + row;
        unsigned short* strow = ST + row * 264;
        if (trow < TT) {
            const float* amr = am + (size_t)trow * TT;

            // hoisted att_map loads: all 60 (+3 tail) issued up front so the
            // HBM latency hides under the max/exp passes below
            float areg[15][4];
            #pragma unroll
            for (int i = 0; i < 15; ++i) {
                const int s0 = (part << 2) + (i << 4);
                areg[i][0] = amr[s0 + 0];
                areg[i][1] = amr[s0 + 1];
                areg[i][2] = amr[s0 + 2];
                areg[i][3] = amr[s0 + 3];
            }
            float at0 = 0.f, at1 = 0.f, at2 = 0.f;
            if (part == 0) { at0 = amr[240]; at1 = amr[241]; at2 = amr[242]; }

            float mx = -1e30f;
            #pragma unroll
            for (int i = 0; i < 15; ++i) {
                const ushort4 u = *(const ushort4*)(strow + (part << 2) + (i << 4));
                mx = fmaxf(fmaxf(fmaxf(fmaxf(mx, b2f(u.x)), b2f(u.y)), b2f(u.z)), b2f(u.w));
            }
            if (part == 0)
                for (int s = 240; s < TT; ++s) mx = fmaxf(mx, b2f(strow[s]));
            mx = fmaxf(mx, __shfl_xor(mx, 1));
            mx = fmaxf(mx, __shfl_xor(mx, 2));
            float l = 0.f;
            #pragma unroll
            for (int i = 0; i < 15; ++i) {
                const int s0 = (part << 2) + (i << 4);
                const ushort4 u = *(const ushort4*)(strow + s0);
                const float e0 = __expf(b2f(u.x) - mx), e1 = __expf(b2f(u.y) - mx);
                const float e2 = __expf(b2f(u.z) - mx), e3 = __expf(b2f(u.w) - mx);
                l += (e0 + e1) + (e2 + e3);
                ushort4 o;
                o.x = f2bf(e0); o.y = f2bf(e1); o.z = f2bf(e2); o.w = f2bf(e3);
                *(ushort4*)(strow + s0) = o;
            }
            if (part == 0)
                for (int s = 240; s < TT; ++s) {
                    const float e = __expf(b2f(strow[s]) - mx);
                    l += e; strow[s] = f2bf(e);
                }
            l += __shfl_xor(l, 1);
            l += __shfl_xor(l, 2);
            const float sw = w / l, aw = 1.f - w;
            #pragma unroll
            for (int i = 0; i < 15; ++i) {
                const int s0 = (part << 2) + (i << 4);
                const ushort4 u = *(const ushort4*)(strow + s0);
                ushort4 o;
                o.x = f2bf(b2f(u.x) * sw + aw * areg[i][0]);
                o.y = f2bf(b2f(u.y) * sw + aw * areg[i][1]);
                o.z = f2bf(b2f(u.z) * sw + aw * areg[i][2]);
                o.w = f2bf(b2f(u.w) * sw + aw * areg[i][3]);
                *(ushort4*)(strow + s0) = o;
            }
            if (part == 0) {
                strow[240] = f2bf(b2f(strow[240]) * sw + aw * at0);
                strow[241] = f2bf(b2f(strow[241]) * sw + aw * at1);
                strow[242] = f2bf(b2f(strow[242]) * sw + aw * at2);
                for (int s = TT; s < 256; ++s) strow[s] = 0;
            }
        } else {
            #pragma unroll
            for (int i = 0; i < 16; ++i)
                *(ushort4*)(strow + (part << 2) + (i << 4)) = make_ushort4(0, 0, 0, 0);
        }
    }
    __syncthreads();

    // ---- Phase 3: O = P @ Vt (wave w -> rows 16w..16w+15), Vt from global ----
    f32x4 oacc[4];
    #pragma unroll
    for (int nj = 0; nj < 4; ++nj) oacc[nj] = (f32x4){0.f, 0.f, 0.f, 0.f};
    const unsigned short* strow3 = ST + ((wave << 4) + lm) * 264;
    const unsigned short* vtg = vt + ((size_t)bhj << 14);
    #pragma unroll 2
    for (int kb8 = 0; kb8 < 8; ++kb8) {
        const bf16x8 pf = *(const bf16x8*)(strow3 + (kb8 << 5) + (lk << 3));
        #pragma unroll
        for (int nj = 0; nj < 4; ++nj) {
            const int d = (nj << 4) + lm;
            const int chunk = (kb8 << 2) + lk;
            const bf16x8 vf = *(const bf16x8*)(vtg + (d << 8) + (chunk << 3));
            oacc[nj] = __builtin_amdgcn_mfma_f32_16x16x32_bf16(pf, vf, oacc[nj], 0, 0, 0);
        }
    }

    const int b = bhj / HJ;
    const int hj = bhj - b * HJ;
    const int h = hj / JJ;
    const int j = hj - h * JJ;
    #pragma unroll
    for (int r = 0; r < 4; ++r) {
        const int t = row0 + (wave << 4) + (lk << 2) + r;
        if (t < TT) {
            unsigned short* orow = ob + (((size_t)((b * TT + t) * JJ + j)) << 9) + (h << 6);
            #pragma unroll
            for (int nj = 0; nj < 4; ++nj)
                orow[(nj << 4) + lm] = f2bf(oacc[nj][r]);
        }
    }
}

// ---------------------------------------------------------------------------
// Kernel 3: bf16 MFMA GEMM  out = ob @ Wp + bias  (Wpt pre-transposed)
// Same 2-phase double-buffered structure as gemm_qkv.
// ---------------------------------------------------------------------------
__global__ __launch_bounds__(256) void gemm_proj(
    const unsigned short* __restrict__ obb, const unsigned short* __restrict__ wt,
    const float* __restrict__ bias, float* __restrict__ out)
{
    __shared__ __align__(16) char smem[32768];   // A0|A1|B0|B1, 8KB each
    char* const A0 = smem;
    char* const A1 = smem + 8192;
    char* const B0 = smem + 16384;
    char* const B1 = smem + 24576;

    const int tid = threadIdx.x;
    const int wave = tid >> 6, lane = tid & 63;
    const int m0 = blockIdx.y << 7, n0 = blockIdx.x << 7;
    const int wr = wave >> 1, wc = wave & 1;

    f32x4 acc[4][4];
    #pragma unroll
    for (int i = 0; i < 4; ++i)
        #pragma unroll
        for (int j = 0; j < 4; ++j) acc[i][j] = (f32x4){0.f, 0.f, 0.f, 0.f};

    const int srow = lane >> 2;
    const int sbyte = (lane & 3) << 4;
    const int arow0 = (wave << 5) + srow;
    const int arow1 = arow0 + 16;
    const size_t am0 = (size_t)min(m0 + arow0, MROWS - 1);
    const size_t am1 = (size_t)min(m0 + arow1, MROWS - 1);
    const char* ab = (const char*)obb;
    const char* wtb = (const char*)wt;

#define STAGEP(Ad, Bd, k0) do { \
    async16(ab + (am0 * 512 + (k0)) * 2 + sbyte, (Ad) + ((wave << 5) << 6)); \
    async16(ab + (am1 * 512 + (k0)) * 2 + sbyte, (Ad) + (((wave << 5) + 16) << 6)); \
    async16(wtb + ((size_t)(n0 + arow0) * 512 + (k0)) * 2 + sbyte, (Bd) + ((wave << 5) << 6)); \
    async16(wtb + ((size_t)(n0 + arow1) * 512 + (k0)) * 2 + sbyte, (Bd) + (((wave << 5) + 16) << 6)); \
} while (0)

#define COMPUTEP(Ap, Bp) do { \
    bf16x8 af[4], bfr[4]; \
    _Pragma("unroll") \
    for (int i = 0; i < 4; ++i) \
        af[i] = *(const bf16x8*)((const unsigned short*)(Ap) + \
            ((wr << 6) + (i << 4) + (lane & 15)) * 32 + ((lane >> 4) << 3)); \
    _Pragma("unroll") \
    for (int j = 0; j < 4; ++j) \
        bfr[j] = *(const bf16x8*)((const unsigned short*)(Bp) + \
            ((wc << 6) + (j << 4) + (lane & 15)) * 32 + ((lane >> 4) << 3)); \
    _Pragma("unroll") \
    for (int i = 0; i < 4; ++i) \
        _Pragma("unroll") \
        for (int j = 0; j < 4; ++j) \
            acc[i][j] = __builtin_amdgcn_mfma_f32_16x16x32_bf16(af[i], bfr[j], acc[i][j], 0, 0, 0); \
} while (0)

    STAGEP(A0, B0, 0);
    __syncthreads();
    #pragma unroll
    for (int t = 0; t < 16; t += 2) {
        STAGEP(A1, B1, (t + 1) << 5);
        COMPUTEP(A0, B0);
        __syncthreads();
        if (t + 2 < 16) STAGEP(A0, B0, (t + 2) << 5);
        COMPUTEP(A1, B1);
        __syncthreads();
    }
#undef STAGEP
#undef COMPUTEP

    // epilogue scratch aliases staging buffers (dead after final barrier)
    float (*Cp)[16][68] = (float (*)[16][68])smem;

    const int ch0 = lane & 15;
    const float4 bvec = *(const float4*)&bias[n0 + (wc << 6) + (ch0 << 2)];
    #pragma unroll
    for (int i = 0; i < 4; ++i) {
        #pragma unroll
        for (int j = 0; j < 4; ++j)
            #pragma unroll
            for (int r = 0; r < 4; ++r)
                Cp[wave][((lane >> 4) << 2) + r][(j << 4) + (lane & 15)] = acc[i][j][r];
        #pragma unroll
        for (int qq = 0; qq < 4; ++qq) {
            const int rr = (qq << 2) + (lane >> 4);
            const int ch = lane & 15;
            float4 val = *(const float4*)&Cp[wave][rr][ch << 2];
            const int m = m0 + (wr << 6) + (i << 4) + rr;
            if (m < MROWS) {
                val.x += bvec.x; val.y += bvec.y; val.z += bvec.z; val.w += bvec.w;
                *(float4*)(out + (size_t)m * 512 + n0 + (wc << 6) + (ch << 2)) = val;
            }
        }
    }
}

// ---------------------------------------------------------------------------
extern "C" void kernel_launch(void* const* d_in, const int* in_sizes, int n_in,
                              void* d_out, int out_size, void* d_ws, size_t ws_size,
                              hipStream_t stream)
{
    const float* x    = (const float*)d_in[0];
    const float* att  = (const float*)d_in[1];
    const float* wgt  = (const float*)d_in[2];
    const float* Wqkv = (const float*)d_in[3];
    const float* Wp   = (const float*)d_in[4];
    const float* bp   = (const float*)d_in[5];
    float* out = (float*)d_out;

    const size_t SZ = (size_t)MROWS * 512;        // 16,920,576
    unsigned short* xb    = (unsigned short*)d_ws;
    unsigned short* wqkvt = xb + SZ;
    unsigned short* wpt   = wqkvt + (size_t)1536 * 512;
    unsigned short* qb    = wpt + (size_t)512 * 512;
    unsigned short* kb    = qb + SZ;
    unsigned short* vb    = kb + SZ;
    unsigned short* ob    = vb + SZ;
    unsigned short* vtb   = ob + SZ;              // 1088*64*256 shorts (~35.7 MB)

    convert_x<<<4096, 256, 0, stream>>>(x, xb, (int)(SZ / 4));
    transpose_w<<<dim3(24, 8), 256, 0, stream>>>(Wqkv, wqkvt, 1536);
    transpose_w<<<dim3(8, 8), 256, 0, stream>>>(Wp, wpt, 512);

    gemm_qkv<<<dim3(12, 259), 256, 0, stream>>>(xb, wqkvt, qb, kb, vb);

    vtrans<<<dim3(1088), 256, 0, stream>>>(vb, vtb);

    attn_mfma<<<dim3(1088 * 4), 256, 0, stream>>>(qb, kb, vtb, att, wgt, ob);

    gemm_proj<<<dim3(4, 259), 256, 0, stream>>>(ob, wpt, bp, out);
}

// Round 4
// 593.799 us; speedup vs baseline: 1.0623x; 1.0106x over previous
//
#include <hip/hip_runtime.h>
#include <hip/hip_bf16.h>
#include <cstddef>
#include <cstdint>

#define NHEADS 8
#define TT 243
#define JJ 17
#define BB 8
#define CC 512
#define HD 64
#define MROWS 33048      // B*T*J
#define TJ 4131          // T*J
#define HJ 136           // H*J

typedef __attribute__((ext_vector_type(8))) short bf16x8;
typedef __attribute__((ext_vector_type(4))) float f32x4;
typedef __attribute__((ext_vector_type(4), aligned(4))) float f32x4u;  // 4B-aligned vec4

__device__ __forceinline__ unsigned short f2bf(float f) {
    return __builtin_bit_cast(unsigned short, __float2bfloat16(f));   // native RNE cvt
}
__device__ __forceinline__ float b2f(unsigned short u) {
    return __uint_as_float(((unsigned)u) << 16);
}
__device__ __forceinline__ void async16(const void* g, void* l) {
    __builtin_amdgcn_global_load_lds(
        (const __attribute__((address_space(1))) void*)g,
        (__attribute__((address_space(3))) void*)l, 16, 0, 0);
}

// ---------------------------------------------------------------------------
// prep: x fp32 -> bf16 (same layout)
// ---------------------------------------------------------------------------
__global__ __launch_bounds__(256) void convert_x(
    const float* __restrict__ in, unsigned short* __restrict__ out, int n4)
{
    for (int i = blockIdx.x * 256 + threadIdx.x; i < n4; i += gridDim.x * 256) {
        const float4 v = *(const float4*)(in + (size_t)i * 4);
        ushort4 o;
        o.x = f2bf(v.x); o.y = f2bf(v.y); o.z = f2bf(v.z); o.w = f2bf(v.w);
        *(ushort4*)(out + (size_t)i * 4) = o;
    }
}

// ---------------------------------------------------------------------------
// prep: W fp32 [512][N] -> bf16 [N][512]  (transpose + convert)
// ---------------------------------------------------------------------------
__global__ __launch_bounds__(256) void transpose_w(
    const float* __restrict__ src, unsigned short* __restrict__ dst, int N)
{
    __shared__ unsigned short tile[64][65];
    const int tid = threadIdx.x;
    const int c = tid & 63, r4 = tid >> 6;
    const int n0 = blockIdx.x << 6, k0 = blockIdx.y << 6;
    #pragma unroll
    for (int p = 0; p < 16; ++p) {
        const int r = (p << 2) + r4;
        tile[r][c] = f2bf(src[(size_t)(k0 + r) * N + n0 + c]);
    }
    __syncthreads();
    #pragma unroll
    for (int p = 0; p < 16; ++p) {
        const int rr = (p << 2) + r4;
        dst[(size_t)(n0 + rr) * 512 + k0 + c] = tile[c][rr];
    }
}

// ---------------------------------------------------------------------------
// Kernel 1: bf16 MFMA GEMM  qkv = xb @ Wqkv  (Wqkvt pre-transposed [1536][512])
// Double-buffered LDS (2-phase). Epilogue scratch aliases staging buffers.
// ---------------------------------------------------------------------------
__global__ __launch_bounds__(256) void gemm_qkv(
    const unsigned short* __restrict__ xb, const unsigned short* __restrict__ wt,
    unsigned short* __restrict__ qb, unsigned short* __restrict__ kb,
    unsigned short* __restrict__ vb)
{
    __shared__ __align__(16) char smem[32768];   // A0|A1|B0|B1, 8KB each
    char* const A0 = smem;
    char* const A1 = smem + 8192;
    char* const B0 = smem + 16384;
    char* const B1 = smem + 24576;

    const int tid = threadIdx.x;
    const int wave = tid >> 6, lane = tid & 63;
    const int m0 = blockIdx.y << 7, n0 = blockIdx.x << 7;
    const int wr = wave >> 1, wc = wave & 1;

    f32x4 acc[4][4];
    #pragma unroll
    for (int i = 0; i < 4; ++i)
        #pragma unroll
        for (int j = 0; j < 4; ++j) acc[i][j] = (f32x4){0.f, 0.f, 0.f, 0.f};

    const int srow = lane >> 2;
    const int sbyte = (lane & 3) << 4;
    const int arow0 = (wave << 5) + srow;
    const int arow1 = arow0 + 16;
    const size_t am0 = (size_t)min(m0 + arow0, MROWS - 1);
    const size_t am1 = (size_t)min(m0 + arow1, MROWS - 1);
    const char* xbb = (const char*)xb;
    const char* wtb = (const char*)wt;

#define STAGEQ(Ad, Bd, k0) do { \
    async16(xbb + (am0 * 512 + (k0)) * 2 + sbyte, (Ad) + ((wave << 5) << 6)); \
    async16(xbb + (am1 * 512 + (k0)) * 2 + sbyte, (Ad) + (((wave << 5) + 16) << 6)); \
    async16(wtb + ((size_t)(n0 + arow0) * 512 + (k0)) * 2 + sbyte, (Bd) + ((wave << 5) << 6)); \
    async16(wtb + ((size_t)(n0 + arow1) * 512 + (k0)) * 2 + sbyte, (Bd) + (((wave << 5) + 16) << 6)); \
} while (0)

#define COMPUTEQ(Ap, Bp) do { \
    bf16x8 af[4], bfr[4]; \
    _Pragma("unroll") \
    for (int i = 0; i < 4; ++i) \
        af[i] = *(const bf16x8*)((const unsigned short*)(Ap) + \
            ((wr << 6) + (i << 4) + (lane & 15)) * 32 + ((lane >> 4) << 3)); \
    _Pragma("unroll") \
    for (int j = 0; j < 4; ++j) \
        bfr[j] = *(const bf16x8*)((const unsigned short*)(Bp) + \
            ((wc << 6) + (j << 4) + (lane & 15)) * 32 + ((lane >> 4) << 3)); \
    _Pragma("unroll") \
    for (int i = 0; i < 4; ++i) \
        _Pragma("unroll") \
        for (int j = 0; j < 4; ++j) \
            acc[i][j] = __builtin_amdgcn_mfma_f32_16x16x32_bf16(af[i], bfr[j], acc[i][j], 0, 0, 0); \
} while (0)

    STAGEQ(A0, B0, 0);
    __syncthreads();
    #pragma unroll
    for (int t = 0; t < 16; t += 2) {
        STAGEQ(A1, B1, (t + 1) << 5);
        COMPUTEQ(A0, B0);
        __syncthreads();
        if (t + 2 < 16) STAGEQ(A0, B0, (t + 2) << 5);
        COMPUTEQ(A1, B1);
        __syncthreads();
    }
#undef STAGEQ
#undef COMPUTEQ

    unsigned short (*Cq)[16][72] = (unsigned short (*)[16][72])smem;

    const int nw = n0 + (wc << 6);
    const int which = nw >> 9;
    const int h = (nw >> 6) & 7;
    unsigned short* const dst = which == 0 ? qb : (which == 1 ? kb : vb);
    #pragma unroll
    for (int i = 0; i < 4; ++i) {
        #pragma unroll
        for (int j = 0; j < 4; ++j)
            #pragma unroll
            for (int r = 0; r < 4; ++r)
                Cq[wave][((lane >> 4) << 2) + r][(j << 4) + (lane & 15)] = f2bf(acc[i][j][r]);
        #pragma unroll
        for (int qq = 0; qq < 4; ++qq) {
            const int rr = (qq << 2) + (lane >> 4);
            const int ch = lane & 15;
            const ushort4 val = *(const ushort4*)&Cq[wave][rr][ch << 2];
            const int m = m0 + (wr << 6) + (i << 4) + rr;
            if (m < MROWS) {
                const int b = m / TJ; const int rm = m - b * TJ;
                const int t = rm / JJ; const int jj = rm - t * JJ;
                const size_t base = (((size_t)((b * NHEADS + h) * JJ + jj) * TT + t) << 6) + (ch << 2);
                *(ushort4*)(dst + base) = val;
            }
        }
    }
}

// ---------------------------------------------------------------------------
// vtrans: vb [bhj][t][64] -> vt [bhj][64][256] (d-major, zero-padded t)
// ---------------------------------------------------------------------------
__global__ __launch_bounds__(256) void vtrans(
    const unsigned short* __restrict__ vb, unsigned short* __restrict__ vt)
{
    __shared__ unsigned short TL[64 * 264];
    const int tid = threadIdx.x;
    const int bhj = blockIdx.x;
    const unsigned short* src = vb + (size_t)bhj * TT * HD;

    {   // zero cols 240..255 (covers the t>=243 padding; 240..242 rewritten)
        const int d = tid >> 2, qq = tid & 3;
        *(ushort4*)(TL + d * 264 + 240 + (qq << 2)) = make_ushort4(0, 0, 0, 0);
    }
    __syncthreads();
    #pragma unroll
    for (int p = 0; p < 16; ++p) {
        const int idxq = tid + (p << 8);
        const int t = idxq >> 4;
        if (t < TT) {
            const int d0 = (idxq & 15) << 2;
            const ushort4 u = *(const ushort4*)(src + t * HD + d0);
            TL[(d0 + 0) * 264 + t] = u.x;
            TL[(d0 + 1) * 264 + t] = u.y;
            TL[(d0 + 2) * 264 + t] = u.z;
            TL[(d0 + 3) * 264 + t] = u.w;
        }
    }
    __syncthreads();
    unsigned short* dst = vt + ((size_t)bhj << 14);
    #pragma unroll
    for (int p = 0; p < 8; ++p) {
        const int cw = tid + (p << 8);           // 2048 chunk-writes
        const int d = cw >> 5, c = cw & 31;
        const ushort4 a = *(const ushort4*)(TL + d * 264 + (c << 3));
        const ushort4 bq = *(const ushort4*)(TL + d * 264 + (c << 3) + 4);
        *(ushort4*)(dst + (d << 8) + (c << 3)) = a;
        *(ushort4*)(dst + (d << 8) + (c << 3) + 4) = bq;
    }
}

// ---------------------------------------------------------------------------
// Kernel 2: MFMA attention. block = (bhj, 64-row tile), 4 waves.
// NEW structure: att_map loads issued at KERNEL TOP, after Q/K frag loads
// (q/k occupy the OLDEST vmcnt slots so phase-1's MFMA wait does not drain
// the att stream). att latency hides under the whole of phase 1; the
// vmcnt(0) drain at the phase-1 barrier lands after the cover.
// Phase2 keeps exp results in registers (no P-intermediate LDS round trip).
// ---------------------------------------------------------------------------
__global__ __launch_bounds__(256, 2) void attn_mfma(
    const unsigned short* __restrict__ qb, const unsigned short* __restrict__ kb,
    const unsigned short* __restrict__ vt, const float* __restrict__ att,
    const float* __restrict__ wptr, unsigned short* __restrict__ ob)
{
    __shared__ unsigned short ST[64 * 264];   // S / P, row-major bf16

    const int tid = threadIdx.x;
    const int wave = tid >> 6, lane = tid & 63;
    const int tile = blockIdx.x & 3, bhj = blockIdx.x >> 2;
    const int row0 = tile << 6;

    const unsigned short* q = qb + (size_t)bhj * TT * HD;
    const unsigned short* k = kb + (size_t)bhj * TT * HD;
    const float* am = att + (size_t)bhj * TT * TT;
    const float w = wptr[0];

    const int lm = lane & 15, lk = lane >> 4;

    // ---- Q/K fragment loads FIRST (oldest vmcnt slots) ----
    bf16x8 qf[4][2];
    #pragma unroll
    for (int mi = 0; mi < 4; ++mi) {
        const int r = min(row0 + (mi << 4) + lm, TT - 1);
        #pragma unroll
        for (int kb2 = 0; kb2 < 2; ++kb2)
            qf[mi][kb2] = *(const bf16x8*)(q + r * HD + (kb2 << 5) + (lk << 3));
    }
    bf16x8 kf[2][4];
    #pragma unroll
    for (int kb2 = 0; kb2 < 2; ++kb2)
        #pragma unroll
        for (int nj = 0; nj < 4; ++nj) {
            const int s = min((wave << 6) + (nj << 4) + lm, TT - 1);
            kf[kb2][nj] = *(const bf16x8*)(k + s * HD + (kb2 << 5) + (lk << 3));
        }

    // ---- att_map stream: issue now, consume in phase 2 (covered by phase 1)
    const int row2 = tid >> 2, part = tid & 3;
    const int trow2 = row0 + row2;
    const float* amr = am + (size_t)min(trow2, TT - 1) * TT;
    float areg[15][4];
    #pragma unroll
    for (int i = 0; i < 15; ++i) {
        const f32x4u av = *(const f32x4u*)(amr + (part << 2) + (i << 4));
        areg[i][0] = av.x; areg[i][1] = av.y; areg[i][2] = av.z; areg[i][3] = av.w;
    }
    float at0 = 0.f, at1 = 0.f, at2 = 0.f;
    if (part == 0) { at0 = amr[240]; at1 = amr[241]; at2 = amr[242]; }

    // ---- Phase 1: S = Q K^T ----
    f32x4 acc[4][4];
    #pragma unroll
    for (int mi = 0; mi < 4; ++mi)
        #pragma unroll
        for (int nj = 0; nj < 4; ++nj) acc[mi][nj] = (f32x4){0.f, 0.f, 0.f, 0.f};
    #pragma unroll
    for (int kb2 = 0; kb2 < 2; ++kb2)
        #pragma unroll
        for (int mi = 0; mi < 4; ++mi)
            #pragma unroll
            for (int nj = 0; nj < 4; ++nj)
                acc[mi][nj] = __builtin_amdgcn_mfma_f32_16x16x32_bf16(qf[mi][kb2], kf[kb2][nj], acc[mi][nj], 0, 0, 0);
    #pragma unroll
    for (int mi = 0; mi < 4; ++mi)
        #pragma unroll
        for (int nj = 0; nj < 4; ++nj)
            #pragma unroll
            for (int r = 0; r < 4; ++r) {
                const int m = (mi << 4) + (lk << 2) + r;
                const int s = (wave << 6) + (nj << 4) + lm;
                ST[m * 264 + s] = f2bf(acc[mi][nj][r] * 0.125f);
            }
    __syncthreads();

    // ---- Phase 2: softmax + blend (4 threads per row); exp kept in regs ----
    {
        unsigned short* strow = ST + row2 * 264;
        if (trow2 < TT) {
            float mx = -1e30f;
            #pragma unroll
            for (int i = 0; i < 15; ++i) {
                const ushort4 u = *(const ushort4*)(strow + (part << 2) + (i << 4));
                mx = fmaxf(fmaxf(fmaxf(fmaxf(mx, b2f(u.x)), b2f(u.y)), b2f(u.z)), b2f(u.w));
            }
            if (part == 0)
                for (int s = 240; s < TT; ++s) mx = fmaxf(mx, b2f(strow[s]));
            mx = fmaxf(mx, __shfl_xor(mx, 1));
            mx = fmaxf(mx, __shfl_xor(mx, 2));

            float er[15][4];
            float l = 0.f;
            #pragma unroll
            for (int i = 0; i < 15; ++i) {
                const int s0 = (part << 2) + (i << 4);
                const ushort4 u = *(const ushort4*)(strow + s0);
                er[i][0] = __expf(b2f(u.x) - mx);
                er[i][1] = __expf(b2f(u.y) - mx);
                er[i][2] = __expf(b2f(u.z) - mx);
                er[i][3] = __expf(b2f(u.w) - mx);
                l += (er[i][0] + er[i][1]) + (er[i][2] + er[i][3]);
            }
            float et0 = 0.f, et1 = 0.f, et2 = 0.f;
            if (part == 0) {
                et0 = __expf(b2f(strow[240]) - mx);
                et1 = __expf(b2f(strow[241]) - mx);
                et2 = __expf(b2f(strow[242]) - mx);
                l += et0 + et1 + et2;
            }
            l += __shfl_xor(l, 1);
            l += __shfl_xor(l, 2);
            const float sw = w / l, aw = 1.f - w;
            #pragma unroll
            for (int i = 0; i < 15; ++i) {
                const int s0 = (part << 2) + (i << 4);
                ushort4 o;
                o.x = f2bf(er[i][0] * sw + aw * areg[i][0]);
                o.y = f2bf(er[i][1] * sw + aw * areg[i][1]);
                o.z = f2bf(er[i][2] * sw + aw * areg[i][2]);
                o.w = f2bf(er[i][3] * sw + aw * areg[i][3]);
                *(ushort4*)(strow + s0) = o;
            }
            if (part == 0) {
                strow[240] = f2bf(et0 * sw + aw * at0);
                strow[241] = f2bf(et1 * sw + aw * at1);
                strow[242] = f2bf(et2 * sw + aw * at2);
                for (int s = TT; s < 256; ++s) strow[s] = 0;
            }
        } else {
            #pragma unroll
            for (int i = 0; i < 16; ++i)
                *(ushort4*)(strow + (part << 2) + (i << 4)) = make_ushort4(0, 0, 0, 0);
        }
    }
    __syncthreads();

    // ---- Phase 3: O = P @ Vt (wave w -> rows 16w..16w+15), Vt from global ----
    f32x4 oacc[4];
    #pragma unroll
    for (int nj = 0; nj < 4; ++nj) oacc[nj] = (f32x4){0.f, 0.f, 0.f, 0.f};
    const unsigned short* strow3 = ST + ((wave << 4) + lm) * 264;
    const unsigned short* vtg = vt + ((size_t)bhj << 14);
    #pragma unroll 2
    for (int kb8 = 0; kb8 < 8; ++kb8) {
        const bf16x8 pf = *(const bf16x8*)(strow3 + (kb8 << 5) + (lk << 3));
        #pragma unroll
        for (int nj = 0; nj < 4; ++nj) {
            const int d = (nj << 4) + lm;
            const int chunk = (kb8 << 2) + lk;
            const bf16x8 vf = *(const bf16x8*)(vtg + (d << 8) + (chunk << 3));
            oacc[nj] = __builtin_amdgcn_mfma_f32_16x16x32_bf16(pf, vf, oacc[nj], 0, 0, 0);
        }
    }

    const int b = bhj / HJ;
    const int hj = bhj - b * HJ;
    const int h = hj / JJ;
    const int j = hj - h * JJ;
    #pragma unroll
    for (int r = 0; r < 4; ++r) {
        const int t = row0 + (wave << 4) + (lk << 2) + r;
        if (t < TT) {
            unsigned short* orow = ob + (((size_t)((b * TT + t) * JJ + j)) << 9) + (h << 6);
            #pragma unroll
            for (int nj = 0; nj < 4; ++nj)
                orow[(nj << 4) + lm] = f2bf(oacc[nj][r]);
        }
    }
}

// ---------------------------------------------------------------------------
// Kernel 3: bf16 MFMA GEMM  out = ob @ Wp + bias  (Wpt pre-transposed)
// ---------------------------------------------------------------------------
__global__ __launch_bounds__(256) void gemm_proj(
    const unsigned short* __restrict__ obb, const unsigned short* __restrict__ wt,
    const float* __restrict__ bias, float* __restrict__ out)
{
    __shared__ __align__(16) char smem[32768];   // A0|A1|B0|B1, 8KB each
    char* const A0 = smem;
    char* const A1 = smem + 8192;
    char* const B0 = smem + 16384;
    char* const B1 = smem + 24576;

    const int tid = threadIdx.x;
    const int wave = tid >> 6, lane = tid & 63;
    const int m0 = blockIdx.y << 7, n0 = blockIdx.x << 7;
    const int wr = wave >> 1, wc = wave & 1;

    f32x4 acc[4][4];
    #pragma unroll
    for (int i = 0; i < 4; ++i)
        #pragma unroll
        for (int j = 0; j < 4; ++j) acc[i][j] = (f32x4){0.f, 0.f, 0.f, 0.f};

    const int srow = lane >> 2;
    const int sbyte = (lane & 3) << 4;
    const int arow0 = (wave << 5) + srow;
    const int arow1 = arow0 + 16;
    const size_t am0 = (size_t)min(m0 + arow0, MROWS - 1);
    const size_t am1 = (size_t)min(m0 + arow1, MROWS - 1);
    const char* ab = (const char*)obb;
    const char* wtb = (const char*)wt;

#define STAGEP(Ad, Bd, k0) do { \
    async16(ab + (am0 * 512 + (k0)) * 2 + sbyte, (Ad) + ((wave << 5) << 6)); \
    async16(ab + (am1 * 512 + (k0)) * 2 + sbyte, (Ad) + (((wave << 5) + 16) << 6)); \
    async16(wtb + ((size_t)(n0 + arow0) * 512 + (k0)) * 2 + sbyte, (Bd) + ((wave << 5) << 6)); \
    async16(wtb + ((size_t)(n0 + arow1) * 512 + (k0)) * 2 + sbyte, (Bd) + (((wave << 5) + 16) << 6)); \
} while (0)

#define COMPUTEP(Ap, Bp) do { \
    bf16x8 af[4], bfr[4]; \
    _Pragma("unroll") \
    for (int i = 0; i < 4; ++i) \
        af[i] = *(const bf16x8*)((const unsigned short*)(Ap) + \
            ((wr << 6) + (i << 4) + (lane & 15)) * 32 + ((lane >> 4) << 3)); \
    _Pragma("unroll") \
    for (int j = 0; j < 4; ++j) \
        bfr[j] = *(const bf16x8*)((const unsigned short*)(Bp) + \
            ((wc << 6) + (j << 4) + (lane & 15)) * 32 + ((lane >> 4) << 3)); \
    _Pragma("unroll") \
    for (int i = 0; i < 4; ++i) \
        _Pragma("unroll") \
        for (int j = 0; j < 4; ++j) \
            acc[i][j] = __builtin_amdgcn_mfma_f32_16x16x32_bf16(af[i], bfr[j], acc[i][j], 0, 0, 0); \
} while (0)

    STAGEP(A0, B0, 0);
    __syncthreads();
    #pragma unroll
    for (int t = 0; t < 16; t += 2) {
        STAGEP(A1, B1, (t + 1) << 5);
        COMPUTEP(A0, B0);
        __syncthreads();
        if (t + 2 < 16) STAGEP(A0, B0, (t + 2) << 5);
        COMPUTEP(A1, B1);
        __syncthreads();
    }
#undef STAGEP
#undef COMPUTEP

    float (*Cp)[16][68] = (float (*)[16][68])smem;

    const int ch0 = lane & 15;
    const float4 bvec = *(const float4*)&bias[n0 + (wc << 6) + (ch0 << 2)];
    #pragma unroll
    for (int i = 0; i < 4; ++i) {
        #pragma unroll
        for (int j = 0; j < 4; ++j)
            #pragma unroll
            for (int r = 0; r < 4; ++r)
                Cp[wave][((lane >> 4) << 2) + r][(j << 4) + (lane & 15)] = acc[i][j][r];
        #pragma unroll
        for (int qq = 0; qq < 4; ++qq) {
            const int rr = (qq << 2) + (lane >> 4);
            const int ch = lane & 15;
            float4 val = *(const float4*)&Cp[wave][rr][ch << 2];
            const int m = m0 + (wr << 6) + (i << 4) + rr;
            if (m < MROWS) {
                val.x += bvec.x; val.y += bvec.y; val.z += bvec.z; val.w += bvec.w;
                *(float4*)(out + (size_t)m * 512 + n0 + (wc << 6) + (ch << 2)) = val;
            }
        }
    }
}

// ---------------------------------------------------------------------------
extern "C" void kernel_launch(void* const* d_in, const int* in_sizes, int n_in,
                              void* d_out, int out_size, void* d_ws, size_t ws_size,
                              hipStream_t stream)
{
    const float* x    = (const float*)d_in[0];
    const float* att  = (const float*)d_in[1];
    const float* wgt  = (const float*)d_in[2];
    const float* Wqkv = (const float*)d_in[3];
    const float* Wp   = (const float*)d_in[4];
    const float* bp   = (const float*)d_in[5];
    float* out = (float*)d_out;

    const size_t SZ = (size_t)MROWS * 512;        // 16,920,576
    unsigned short* xb    = (unsigned short*)d_ws;
    unsigned short* wqkvt = xb + SZ;
    unsigned short* wpt   = wqkvt + (size_t)1536 * 512;
    unsigned short* qb    = wpt + (size_t)512 * 512;
    unsigned short* kb    = qb + SZ;
    unsigned short* vb    = kb + SZ;
    unsigned short* ob    = vb + SZ;
    unsigned short* vtb   = ob + SZ;              // 1088*64*256 shorts (~35.7 MB)

    convert_x<<<4096, 256, 0, stream>>>(x, xb, (int)(SZ / 4));
    transpose_w<<<dim3(24, 8), 256, 0, stream>>>(Wqkv, wqkvt, 1536);
    transpose_w<<<dim3(8, 8), 256, 0, stream>>>(Wp, wpt, 512);

    gemm_qkv<<<dim3(12, 259), 256, 0, stream>>>(xb, wqkvt, qb, kb, vb);

    vtrans<<<dim3(1088), 256, 0, stream>>>(vb, vtb);

    attn_mfma<<<dim3(1088 * 4), 256, 0, stream>>>(qb, kb, vtb, att, wgt, ob);

    gemm_proj<<<dim3(4, 259), 256, 0, stream>>>(ob, wpt, bp, out);
}